// Round 5
// baseline (558.443 us; speedup 1.0000x reference)
//
#include <hip/hip_runtime.h>
#include <stdint.h>

// out = x @ dequant(W)^T + bias
// x: [M,K] fp32 (M=B*S=8192), W_q: [N,K] int32 codes in [0,4),
// scale/zp: [N,K/G] fp32 (G=64), bias: [N] fp32, out: [M,N] fp32.
//
// R7: R6's per-phase interleave + REAL pipeline depth. TK=32 with a 4-deep
// LDS ring (4 x 16 KB per operand = 128 KB). 2 phases/tile, 16 MFMA each;
// block-cooperative staging 2 gloads/thread/phase (p0: A(t+3), p1: B(t+3));
// counted vmcnt(8) once per tile — drains only t+1's loads (issued at t-2,
// ~4 phases old), leaves 8 in flight. Never vmcnt(0) in steady state (m218:
// counted-vs-drain0 = +38%). WAR: stage slot (t+3)&3=(t-1)&3, t-1 reads
// done at lgkm0 before barrier#2(t-1,p1) which stagers cross first.
// R4-proven chunk swizzle (c ^= (row>>1)&3 on 64B rows), 0 conflicts.

typedef __attribute__((ext_vector_type(4))) float  f32x4;
typedef __attribute__((ext_vector_type(4))) int    i32x4;
typedef __attribute__((ext_vector_type(8))) __bf16 bf16x8;
typedef __attribute__((ext_vector_type(8))) unsigned short u16x8;

__device__ __forceinline__ unsigned short f2bf(float f) {
  unsigned u = __builtin_bit_cast(unsigned, f);
  u += 0x7fffu + ((u >> 16) & 1u);   // round-to-nearest-even
  return (unsigned short)(u >> 16);
}

__device__ __forceinline__ void async16(const void* g, void* l) {
  __builtin_amdgcn_global_load_lds(
      (const __attribute__((address_space(1))) unsigned int*)g,
      (__attribute__((address_space(3))) unsigned int*)l, 16, 0, 0);
}

// ---------------- fused prepass: x->bf16 and dequant W->bf16 ----------------
__global__ __launch_bounds__(256) void prep_kernel(
    const float* __restrict__ x, unsigned short* __restrict__ xb, int xunits,
    const int* __restrict__ wq, const float* __restrict__ scale,
    const float* __restrict__ zp, unsigned short* __restrict__ wb,
    int wunits, int K, int G, int ng) {
  const int stride = gridDim.x * 256;
  const int i0 = blockIdx.x * 256 + threadIdx.x;
  for (int u = i0; u < xunits; u += stride) {
    const f32x4* xp = (const f32x4*)x + (size_t)u * 2;
    f32x4 a = xp[0], b = xp[1];
    u16x8 o;
    o[0] = f2bf(a[0]); o[1] = f2bf(a[1]); o[2] = f2bf(a[2]); o[3] = f2bf(a[3]);
    o[4] = f2bf(b[0]); o[5] = f2bf(b[1]); o[6] = f2bf(b[2]); o[7] = f2bf(b[3]);
    *((u16x8*)xb + u) = o;
  }
  for (int u = i0; u < wunits; u += stride) {
    int k8 = u * 8;
    int n = k8 / K, kk = k8 % K;
    int g = kk / G;
    float s  = scale[(size_t)n * ng + g];
    float bz = -zp[(size_t)n * ng + g] * s;   // w = q*s + bz
    const i32x4* wp = (const i32x4*)wq + (size_t)u * 2;
    i32x4 qa = wp[0], qb = wp[1];
    u16x8 o;
    o[0] = f2bf((float)qa[0] * s + bz); o[1] = f2bf((float)qa[1] * s + bz);
    o[2] = f2bf((float)qa[2] * s + bz); o[3] = f2bf((float)qa[3] * s + bz);
    o[4] = f2bf((float)qb[0] * s + bz); o[5] = f2bf((float)qb[1] * s + bz);
    o[6] = f2bf((float)qb[2] * s + bz); o[7] = f2bf((float)qb[3] * s + bz);
    *((u16x8*)wb + u) = o;
  }
}

// ---------------- main GEMM: C[M,N] = A[M,K] * B[N,K]^T + bias ----------------
#define BM 256
#define BN 256
#define TK 32
#define RSZ (256 * 32)   // region elems (256 rows x 32 cols = 16 KB)

__global__ __launch_bounds__(512, 2) void gemm_bt_kernel(
    const unsigned short* __restrict__ A,   // M x K bf16
    const unsigned short* __restrict__ B,   // N x K bf16
    const float* __restrict__ bias,
    float* __restrict__ C, int M, int N, int K) {
  // 4-deep ring: 64 KB per operand, 128 KB total.
  __shared__ unsigned short As[4 * RSZ];
  __shared__ unsigned short Bs[4 * RSZ];

  const int tid  = threadIdx.x;
  const int lane = tid & 63;
  const int wave = tid >> 6;                // 8 waves: 2 (M) x 4 (N)
  const int wm = wave >> 2, wn = wave & 3;  // wave tile: 128 (M) x 64 (N)
  const int q = lane >> 4, r = lane & 15;   // MFMA k-quad / row-in-16

  // XCD-aware bijective swizzle (nwg % 8 == 0).
  int id = blockIdx.x;
  {
    int nwg = gridDim.x;
    if ((nwg & 7) == 0) id = (id & 7) * (nwg >> 3) + (id >> 3);
  }
  const int nbx = N / BN;
  const int m0 = (id / nbx) * BM;
  const int n0 = (id % nbx) * BN;

  // Staging: thread tid owns LDS (row = tid>>2 of shot, chunk = tid&3);
  // 2 shots per region (rows 0-127, 128-255). Global source pre-swizzled:
  // stored chunk s of row holds global chunk s ^ ((row>>1)&3).
  const int srow = tid >> 2;                      // 0..127
  const int gch  = (tid & 3) ^ ((tid >> 3) & 3);  // (tid&3) ^ ((srow>>1)&3)
  const unsigned short* aG = A + (size_t)(m0 + srow) * K + gch * 8;
  const unsigned short* bG = B + (size_t)(n0 + srow) * K + gch * 8;
  const size_t rb = (size_t)128 * K;              // shot-1 global row offset

  unsigned short* aS = As + tid * 8;
  unsigned short* bS = Bs + tid * 8;

#define STG_A(slot, kk) { \
    unsigned short* d = aS + (slot) * RSZ; \
    async16(aG + (kk), d); async16(aG + rb + (kk), d + 4096); }
#define STG_B(slot, kk) { \
    unsigned short* d = bS + (slot) * RSZ; \
    async16(bG + (kk), d); async16(bG + rb + (kk), d + 4096); }

  // Read side: global chunk c of row R stored at chunk c ^ ((R>>1)&3);
  // frag rows are 16-aligned + r, so key = (r>>1)&3 (const per lane).
  const int qc8  = ((q ^ ((r >> 1) & 3))) * 8;
  const int aoff = (wm * 128 + r) * 32 + qc8;     // + mi*512
  const int boff = (wn * 64  + r) * 32 + qc8;     // + nj*512

  f32x4 acc[8][4] = {};
  const int NT = K / TK;

  // Prologue: stage tiles 0..2 (FIFO: A0,B0,A1,B1,A2,B2), drain tile 0 only.
  STG_A(0, 0) STG_B(0, 0)
  if (NT > 1) { STG_A(1, TK) STG_B(1, TK) }
  if (NT > 2) { STG_A(2, 2 * TK) STG_B(2, 2 * TK) }
  if (NT > 2)      asm volatile("s_waitcnt vmcnt(8)" ::: "memory");
  else if (NT > 1) asm volatile("s_waitcnt vmcnt(4)" ::: "memory");
  else             asm volatile("s_waitcnt vmcnt(0)" ::: "memory");
  __builtin_amdgcn_s_barrier();
  asm volatile("" ::: "memory");

#pragma unroll 1
  for (int t = 0; t < NT; ++t) {
    const int slot = t & 3;
    const bool pf = (t + 3 < NT);
    const unsigned short* Ar = As + slot * RSZ;
    const unsigned short* Br = Bs + slot * RSZ;

    bf16x8 bf[4], af[4];

    // ---------------- phase 0: b-frags + a mi0-3 ----------------
#pragma unroll
    for (int nj = 0; nj < 4; ++nj)
      bf[nj] = *(const bf16x8*)&Br[boff + nj * 512];
#pragma unroll
    for (int mi = 0; mi < 4; ++mi)
      af[mi] = *(const bf16x8*)&Ar[aoff + mi * 512];
    if (pf) STG_A((t + 3) & 3, (t + 3) * TK)
    __builtin_amdgcn_s_barrier();
    asm volatile("s_waitcnt lgkmcnt(0)" ::: "memory");
    __builtin_amdgcn_s_setprio(1);
#pragma unroll
    for (int mi = 0; mi < 4; ++mi)
#pragma unroll
      for (int nj = 0; nj < 4; ++nj)
        acc[mi][nj] = __builtin_amdgcn_mfma_f32_16x16x32_bf16(
            af[mi], bf[nj], acc[mi][nj], 0, 0, 0);
    __builtin_amdgcn_s_setprio(0);
    asm volatile("" ::: "memory");
    __builtin_amdgcn_s_barrier();
    asm volatile("" ::: "memory");

    // ---------------- phase 1: a mi4-7 ----------------
#pragma unroll
    for (int mi = 0; mi < 4; ++mi)
      af[mi] = *(const bf16x8*)&Ar[aoff + (4 + mi) * 512];
    if (pf) STG_B((t + 3) & 3, (t + 3) * TK)
    // Counted drain: need tile t+1 resident (issued at t-2, ~4 phases old);
    // leave A/B of t+2,t+3 (8 loads) in flight. Tail: 4 -> 0.
    {
      int rem = ((t + 3 < NT ? t + 3 : NT - 1)) - (t + 1);
      if (rem >= 2)      asm volatile("s_waitcnt vmcnt(8)" ::: "memory");
      else if (rem == 1) asm volatile("s_waitcnt vmcnt(4)" ::: "memory");
      else               asm volatile("s_waitcnt vmcnt(0)" ::: "memory");
    }
    __builtin_amdgcn_s_barrier();
    asm volatile("s_waitcnt lgkmcnt(0)" ::: "memory");
    __builtin_amdgcn_s_setprio(1);
#pragma unroll
    for (int mi = 0; mi < 4; ++mi)
#pragma unroll
      for (int nj = 0; nj < 4; ++nj)
        acc[4 + mi][nj] = __builtin_amdgcn_mfma_f32_16x16x32_bf16(
            af[mi], bf[nj], acc[4 + mi][nj], 0, 0, 0);
    __builtin_amdgcn_s_setprio(0);
    asm volatile("" ::: "memory");
    __builtin_amdgcn_s_barrier();
    asm volatile("" ::: "memory");
  }

  // epilogue: C/D layout col = lane&15, row = quad*4 + reg
  float bv[4];
#pragma unroll
  for (int j = 0; j < 4; ++j) bv[j] = bias[n0 + wn * 64 + j * 16 + r];
#pragma unroll
  for (int i = 0; i < 8; ++i) {
    int mbase = m0 + wm * 128 + i * 16 + q * 4;
#pragma unroll
    for (int e = 0; e < 4; ++e) {
      float* crow = C + (size_t)(mbase + e) * N + n0 + wn * 64 + r;
#pragma unroll
      for (int j = 0; j < 4; ++j)
        crow[j * 16] = acc[i][j][e] + bv[j];
    }
  }
}

// ---------------- correctness fallback ----------------
__global__ __launch_bounds__(256) void naive_kernel(
    const float* __restrict__ x, const int* __restrict__ wq,
    const float* __restrict__ scale, const float* __restrict__ zp,
    const float* __restrict__ bias, float* __restrict__ out,
    int M, int N, int K, int G) {
  int idx = blockIdx.x * 256 + threadIdx.x;
  if (idx >= M * N) return;
  int m = idx / N, n = idx % N;
  const float* xr = x + (size_t)m * K;
  const int* wr = wq + (size_t)n * K;
  int ng = K / G;
  float acc = 0.f;
  for (int g = 0; g < ng; ++g) {
    float s = scale[(size_t)n * ng + g];
    float b = -zp[(size_t)n * ng + g] * s;
    for (int k = 0; k < G; ++k)
      acc += xr[g * G + k] * ((float)wr[g * G + k] * s + b);
  }
  out[idx] = acc + bias[n];
}

extern "C" void kernel_launch(void* const* d_in, const int* in_sizes, int n_in,
                              void* d_out, int out_size, void* d_ws, size_t ws_size,
                              hipStream_t stream) {
  const float* x     = (const float*)d_in[0];
  const int*   wq    = (const int*)d_in[1];
  const float* scale = (const float*)d_in[2];
  const float* zp    = (const float*)d_in[3];
  const float* bias  = (const float*)d_in[4];
  float* out = (float*)d_out;

  const int N  = in_sizes[4];
  const int K  = in_sizes[1] / N;
  const int ng = in_sizes[2] / N;
  const int G  = K / ng;
  const int M  = in_sizes[0] / K;

  size_t xb_bytes = (size_t)M * K * 2;
  size_t wb_bytes = (size_t)N * K * 2;
  bool divisible = (M % BM == 0) && (N % BN == 0) && (K % TK == 0) &&
                   (G % 8 == 0);
  if (ws_size < xb_bytes + wb_bytes || !divisible) {
    int total = M * N;
    naive_kernel<<<dim3((total + 255) / 256), dim3(256), 0, stream>>>(
        x, wq, scale, zp, bias, out, M, N, K, G);
    return;
  }

  unsigned short* xb = (unsigned short*)d_ws;
  unsigned short* wb = (unsigned short*)((char*)d_ws + xb_bytes);

  int xunits = M * K / 8;
  int wunits = N * K / 8;
  prep_kernel<<<dim3(2048), dim3(256), 0, stream>>>(
      x, xb, xunits, wq, scale, zp, wb, wunits, K, G, ng);

  dim3 grid((M / BM) * (N / BN));
  gemm_bt_kernel<<<grid, dim3(512), 0, stream>>>(xb, wb, bias, out, M, N, K);
}